// Round 6
// baseline (149.150 us; speedup 1.0000x reference)
//
#include <hip/hip_runtime.h>
#include <math.h>

#define M_PTS   2048
#define N_VOX   65536
#define VPT     4                    // voxels per lane
#define VPB     256                  // voxels per block (64 lanes * VPT)
#define NBLK    (N_VOX / VPB)        // 256 blocks (1 per CU)
#define NWAVES  16                   // 1024-thread blocks
#define CHUNK   (M_PTS / NWAVES)     // 128 points per wave

// ws layout (floats):
//   [0, 8192)   transformed points as float4 (x,y,z,h)/RES, h = 0.5*|p/RES|^2
//   [8192,8196) accumulators {pred_sum, fo_sum, mask_occ_sum, mask_sum}
//   [8196]      ticket counter (int)

__device__ __forceinline__ void compute_W(const float* __restrict__ quat,
                                          const float* __restrict__ tran,
                                          const float* __restrict__ view,
                                          float* W) {
    float q0 = quat[0], q1 = quat[1], q2 = quat[2], q3 = quat[3];
    float nq = q0*q0 + q1*q1 + q2*q2 + q3*q3;
    float s = sqrtf(2.0f / nq);
    q0 *= s; q1 *= s; q2 *= s; q3 *= s;
    float E[16];
    E[0]  = 1.0f - q2*q2 - q3*q3; E[1]  = q1*q2 - q3*q0;        E[2]  = q1*q3 + q2*q0;        E[3]  = tran[0];
    E[4]  = q1*q2 + q3*q0;        E[5]  = 1.0f - q1*q1 - q3*q3; E[6]  = q2*q3 - q1*q0;        E[7]  = tran[1];
    E[8]  = q1*q3 - q2*q0;        E[9]  = q2*q3 + q1*q0;        E[10] = 1.0f - q1*q1 - q2*q2; E[11] = tran[2];
    E[12] = 0.0f; E[13] = 0.0f; E[14] = 0.0f; E[15] = 1.0f;

    float m[16], inv[16];
    #pragma unroll
    for (int i = 0; i < 16; i++) m[i] = view[i];

    inv[0]  =  m[5]*m[10]*m[15] - m[5]*m[11]*m[14] - m[9]*m[6]*m[15] + m[9]*m[7]*m[14] + m[13]*m[6]*m[11] - m[13]*m[7]*m[10];
    inv[4]  = -m[4]*m[10]*m[15] + m[4]*m[11]*m[14] + m[8]*m[6]*m[15] - m[8]*m[7]*m[14] - m[12]*m[6]*m[11] + m[12]*m[7]*m[10];
    inv[8]  =  m[4]*m[9]*m[15]  - m[4]*m[11]*m[13] - m[8]*m[5]*m[15] + m[8]*m[7]*m[13] + m[12]*m[5]*m[11] - m[12]*m[7]*m[9];
    inv[12] = -m[4]*m[9]*m[14]  + m[4]*m[10]*m[13] + m[8]*m[5]*m[14] - m[8]*m[6]*m[13] - m[12]*m[5]*m[10] + m[12]*m[6]*m[9];
    inv[1]  = -m[1]*m[10]*m[15] + m[1]*m[11]*m[14] + m[9]*m[2]*m[15] - m[9]*m[3]*m[14] - m[13]*m[2]*m[11] + m[13]*m[3]*m[10];
    inv[5]  =  m[0]*m[10]*m[15] - m[0]*m[11]*m[14] - m[8]*m[2]*m[15] + m[8]*m[3]*m[14] + m[12]*m[2]*m[11] - m[12]*m[3]*m[10];
    inv[9]  = -m[0]*m[9]*m[15]  + m[0]*m[11]*m[13] + m[8]*m[1]*m[15] - m[8]*m[3]*m[13] - m[12]*m[1]*m[11] + m[12]*m[3]*m[9];
    inv[13] =  m[0]*m[9]*m[14]  - m[0]*m[10]*m[13] - m[8]*m[1]*m[14] + m[8]*m[2]*m[13] + m[12]*m[1]*m[10] - m[12]*m[2]*m[9];
    inv[2]  =  m[1]*m[6]*m[15]  - m[1]*m[7]*m[14]  - m[5]*m[2]*m[15] + m[5]*m[3]*m[14] + m[13]*m[2]*m[7]  - m[13]*m[3]*m[6];
    inv[6]  = -m[0]*m[6]*m[15]  + m[0]*m[7]*m[14]  + m[4]*m[2]*m[15] - m[4]*m[3]*m[14] - m[12]*m[2]*m[7]  + m[12]*m[3]*m[6];
    inv[10] =  m[0]*m[5]*m[15]  - m[0]*m[7]*m[13]  - m[4]*m[1]*m[15] + m[4]*m[3]*m[13] + m[12]*m[1]*m[7]  - m[12]*m[3]*m[5];
    inv[14] = -m[0]*m[5]*m[14]  + m[0]*m[6]*m[13]  + m[4]*m[1]*m[14] - m[4]*m[2]*m[13] - m[12]*m[1]*m[6]  + m[12]*m[2]*m[5];
    inv[3]  = -m[1]*m[6]*m[11]  + m[1]*m[7]*m[10]  + m[5]*m[2]*m[11] - m[5]*m[3]*m[10] - m[9]*m[2]*m[7]   + m[9]*m[3]*m[6];
    inv[7]  =  m[0]*m[6]*m[11]  - m[0]*m[7]*m[10]  - m[4]*m[2]*m[11] + m[4]*m[3]*m[10] + m[8]*m[2]*m[7]   - m[8]*m[3]*m[6];
    inv[11] = -m[0]*m[5]*m[11]  + m[0]*m[7]*m[9]   + m[4]*m[1]*m[11] - m[4]*m[3]*m[9]  - m[8]*m[1]*m[7]   + m[8]*m[3]*m[5];
    inv[15] =  m[0]*m[5]*m[10]  - m[0]*m[6]*m[9]   - m[4]*m[1]*m[10] + m[4]*m[2]*m[9]  + m[8]*m[1]*m[6]   - m[8]*m[2]*m[5];

    float det = m[0]*inv[0] + m[1]*inv[4] + m[2]*inv[8] + m[3]*inv[12];
    float rdet = 1.0f / det;

    #pragma unroll
    for (int r = 0; r < 4; r++) {
        #pragma unroll
        for (int c = 0; c < 4; c++) {
            float a = 0.0f;
            #pragma unroll
            for (int k = 0; k < 4; k++) a += inv[4*r+k] * rdet * E[4*k+c];
            W[4*r+c] = a;
        }
    }
}

// 8 blocks x 256 threads: transform 2048 model points into ws; zero acc+ticket.
__global__ __launch_bounds__(256) void k_prep(const float* __restrict__ quat,
                                              const float* __restrict__ tran,
                                              const float* __restrict__ model,
                                              const float* __restrict__ view,
                                              float4* __restrict__ pts,
                                              float* __restrict__ acc,
                                              int* __restrict__ ticket) {
    float W[16];
    compute_W(quat, tran, view, W);

    const int i = blockIdx.x * 256 + threadIdx.x;   // 0..2047
    float x = model[3*i + 0];
    float y = model[3*i + 1];
    float z = model[3*i + 2];
    float X  = W[0]*x + W[1]*y + W[2]*z  + W[3];
    float Y  = W[4]*x + W[5]*y + W[6]*z  + W[7];
    float Z  = W[8]*x + W[9]*y + W[10]*z + W[11];
    float Wd = W[12]*x + W[13]*y + W[14]*z + W[15];
    float rw = 2.0f / Wd;                 // (1/w) * (1/RES)
    float px = X * rw, py = Y * rw, pz = Z * rw;
    float h  = 0.5f * (px*px + py*py + pz*pz);
    pts[i] = make_float4(px, py, pz, h);

    if (blockIdx.x == 0 && threadIdx.x == 0) {
        acc[0] = 0.0f; acc[1] = 0.0f; acc[2] = 0.0f; acc[3] = 0.0f;
        *ticket = 0;
    }
}

// 256 blocks x 1024 threads: 16 waves sweep 128-pt chunks via wave-uniform
// global loads (1 coalesced 16B request each, L1-resident after first sweep).
__global__ __launch_bounds__(1024) void k_main(const float4* __restrict__ pts,
                                               const float* __restrict__ centers,
                                               const float* __restrict__ freev,
                                               const float* __restrict__ occ_other,
                                               const float* __restrict__ masks,
                                               float* __restrict__ acc,
                                               int* __restrict__ ticket,
                                               float* __restrict__ out) {
    __shared__ float pmin[NWAVES * VPB];    // 16 KB
    __shared__ float sred[16];

    const int tid  = threadIdx.x;
    const int lane = tid & 63;
    const int wave = tid >> 6;     // uniform at runtime; divergent to the compiler -> VMEM loads
    const int vbase = blockIdx.x * VPB + lane * VPT;

    float nx[VPT], ny[VPT], nz[VPT], mm[VPT];
    #pragma unroll
    for (int k = 0; k < VPT; k++) {
        int g = vbase + k;
        nx[k] = -centers[3*g + 0] * 2.0f;   // -(c/RES)
        ny[k] = -centers[3*g + 1] * 2.0f;
        nz[k] = -centers[3*g + 2] * 2.0f;
        mm[k] = 1e30f;
    }

    const float4* base = pts + wave * CHUNK;

    // 8-deep unroll: compiler batches 8 global_load_dwordx4 in flight (vmcnt),
    // VALU (4 inst per point per voxel) overlaps the VMEM pipe.
    #pragma unroll 8
    for (int j = 0; j < CHUNK; ++j) {
        float4 p = base[j];                 // all 64 lanes same addr -> 1 request
        // t = h - c.p ; d2 = |c|^2 + 2t (monotone in t)
        #pragma unroll
        for (int k = 0; k < VPT; k++)
            mm[k] = fminf(mm[k], fmaf(nx[k], p.x, fmaf(ny[k], p.y, fmaf(nz[k], p.z, p.w))));
    }

    #pragma unroll
    for (int k = 0; k < VPT; k++)
        pmin[wave * VPB + lane * VPT + k] = mm[k];
    __syncthreads();

    // ---- epilogue: threads 0..255; thread t owns local voxel t ----
    if (tid < VPB) {
        const int g = blockIdx.x * VPB + tid;
        float m = 1e30f;
        #pragma unroll
        for (int c = 0; c < NWAVES; c++)
            m = fminf(m, pmin[c * VPB + tid]);
        float cx = centers[3*g + 0] * 2.0f;
        float cy = centers[3*g + 1] * 2.0f;
        float cz = centers[3*g + 2] * 2.0f;
        float c2 = cx*cx + cy*cy + cz*cz;
        float d2 = fmaf(2.0f, m, c2);
        float dmin = fminf(sqrtf(fmaxf(d2, 0.0f)), 0.25f);   // clamp at RES/2
        float occ  = fmaxf(1.0f - 4.0f * dmin, 0.0f);

        float mk = masks[g];
        float v0 = occ;
        float v1 = (freev[g] + occ_other[g]) * occ;
        float v2 = mk * occ;
        float v3 = mk;

        #pragma unroll
        for (int off = 32; off > 0; off >>= 1) {
            v0 += __shfl_down(v0, off);
            v1 += __shfl_down(v1, off);
            v2 += __shfl_down(v2, off);
            v3 += __shfl_down(v3, off);
        }
        if (lane == 0) {
            sred[wave*4 + 0] = v0;
            sred[wave*4 + 1] = v1;
            sred[wave*4 + 2] = v2;
            sred[wave*4 + 3] = v3;
        }
    }
    __syncthreads();

    // ---- device-level accumulate + last-block finalize (fence/ticket) ----
    if (tid < 4) {
        float s = sred[tid] + sred[4 + tid] + sred[8 + tid] + sred[12 + tid];
        atomicAdd(&acc[tid], s);            // lanes 0..3 of wave 0
    }
    __threadfence();                        // release: acc adds visible before ticket
    if (tid == 0) {
        int old = atomicAdd(ticket, 1);
        if (old == NBLK - 1) {              // last block to finish
            __threadfence();                // acquire
            float ps = atomicAdd(&acc[0], 0.0f);
            float fo = atomicAdd(&acc[1], 0.0f);
            float mo = atomicAdd(&acc[2], 0.0f);
            float ms = atomicAdd(&acc[3], 0.0f);
            float t1 = (ps > 0.0f) ? (fo / ps) : 0.0f;
            float t2 = (ms > 0.0f) ? (mo / ms) : 0.0f;
            out[0] = t1 - t2;
        }
    }
}

extern "C" void kernel_launch(void* const* d_in, const int* in_sizes, int n_in,
                              void* d_out, int out_size, void* d_ws, size_t ws_size,
                              hipStream_t stream) {
    const float* quat      = (const float*)d_in[0];
    const float* tran      = (const float*)d_in[1];
    const float* model     = (const float*)d_in[2];
    const float* view      = (const float*)d_in[3];
    const float* centers   = (const float*)d_in[4];
    const float* freev     = (const float*)d_in[5];
    const float* occ_other = (const float*)d_in[6];
    const float* masks     = (const float*)d_in[7];
    float* out = (float*)d_out;
    float* wsf = (float*)d_ws;

    float4* pts    = (float4*)wsf;          // 2048 float4
    float*  acc    = wsf + 8192;            // 4 floats
    int*    ticket = (int*)(wsf + 8196);

    k_prep<<<M_PTS / 256, 256, 0, stream>>>(quat, tran, model, view, pts, acc, ticket);
    k_main<<<NBLK, 1024, 0, stream>>>(pts, centers, freev, occ_other, masks,
                                      acc, ticket, out);
}

// Round 7
// 145.701 us; speedup vs baseline: 1.0237x; 1.0237x over previous
//
#include <hip/hip_runtime.h>
#include <math.h>

#define M_PTS   2048
#define N_VOX   65536
#define VPT     4                    // voxels per lane
#define VPB     256                  // voxels per block (64 lanes * VPT)
#define NBLK    (N_VOX / VPB)        // 256 blocks (1 per CU)
#define NWAVES  16                   // 1024-thread blocks, 4 waves/SIMD
#define CHUNK   (M_PTS / NWAVES)     // 128 points per wave

// ws layout (floats): [0..3] accumulators {pred_sum, fo_sum, mask_occ_sum, mask_sum}
//                     [4]    ticket counter (int)

__global__ __launch_bounds__(1024, 4) void k_fused(const float* __restrict__ quat,
                                                   const float* __restrict__ tran,
                                                   const float* __restrict__ model,
                                                   const float* __restrict__ view,
                                                   const float* __restrict__ centers,
                                                   const float* __restrict__ freev,
                                                   const float* __restrict__ occ_other,
                                                   const float* __restrict__ masks,
                                                   float* __restrict__ acc,
                                                   int* __restrict__ ticket,
                                                   float* __restrict__ out) {
    __shared__ float4 sp[M_PTS];             // (x,y,z)/RES, h = 0.5*|p/RES|^2  -> 32 KB
    __shared__ float  pmin[NWAVES * VPB];    // [chunk][local voxel]            -> 16 KB
    __shared__ float  sred[16];              // cross-wave sum combine

    const int tid = threadIdx.x;

    // ---- per-block uniform prep: W = inv(view) * quat_matrix (redundant on all threads) ----
    float W[16];
    {
        float q0 = quat[0], q1 = quat[1], q2 = quat[2], q3 = quat[3];
        float nq = q0*q0 + q1*q1 + q2*q2 + q3*q3;
        float s = sqrtf(2.0f / nq);
        q0 *= s; q1 *= s; q2 *= s; q3 *= s;
        float E[16];
        E[0]  = 1.0f - q2*q2 - q3*q3; E[1]  = q1*q2 - q3*q0;        E[2]  = q1*q3 + q2*q0;        E[3]  = tran[0];
        E[4]  = q1*q2 + q3*q0;        E[5]  = 1.0f - q1*q1 - q3*q3; E[6]  = q2*q3 - q1*q0;        E[7]  = tran[1];
        E[8]  = q1*q3 - q2*q0;        E[9]  = q2*q3 + q1*q0;        E[10] = 1.0f - q1*q1 - q2*q2; E[11] = tran[2];
        E[12] = 0.0f; E[13] = 0.0f; E[14] = 0.0f; E[15] = 1.0f;

        float m[16], inv[16];
        #pragma unroll
        for (int i = 0; i < 16; i++) m[i] = view[i];

        inv[0]  =  m[5]*m[10]*m[15] - m[5]*m[11]*m[14] - m[9]*m[6]*m[15] + m[9]*m[7]*m[14] + m[13]*m[6]*m[11] - m[13]*m[7]*m[10];
        inv[4]  = -m[4]*m[10]*m[15] + m[4]*m[11]*m[14] + m[8]*m[6]*m[15] - m[8]*m[7]*m[14] - m[12]*m[6]*m[11] + m[12]*m[7]*m[10];
        inv[8]  =  m[4]*m[9]*m[15]  - m[4]*m[11]*m[13] - m[8]*m[5]*m[15] + m[8]*m[7]*m[13] + m[12]*m[5]*m[11] - m[12]*m[7]*m[9];
        inv[12] = -m[4]*m[9]*m[14]  + m[4]*m[10]*m[13] + m[8]*m[5]*m[14] - m[8]*m[6]*m[13] - m[12]*m[5]*m[10] + m[12]*m[6]*m[9];
        inv[1]  = -m[1]*m[10]*m[15] + m[1]*m[11]*m[14] + m[9]*m[2]*m[15] - m[9]*m[3]*m[14] - m[13]*m[2]*m[11] + m[13]*m[3]*m[10];
        inv[5]  =  m[0]*m[10]*m[15] - m[0]*m[11]*m[14] - m[8]*m[2]*m[15] + m[8]*m[3]*m[14] + m[12]*m[2]*m[11] - m[12]*m[3]*m[10];
        inv[9]  = -m[0]*m[9]*m[15]  + m[0]*m[11]*m[13] + m[8]*m[1]*m[15] - m[8]*m[3]*m[13] - m[12]*m[1]*m[11] + m[12]*m[3]*m[9];
        inv[13] =  m[0]*m[9]*m[14]  - m[0]*m[10]*m[13] - m[8]*m[1]*m[14] + m[8]*m[2]*m[13] + m[12]*m[1]*m[10] - m[12]*m[2]*m[9];
        inv[2]  =  m[1]*m[6]*m[15]  - m[1]*m[7]*m[14]  - m[5]*m[2]*m[15] + m[5]*m[3]*m[14] + m[13]*m[2]*m[7]  - m[13]*m[3]*m[6];
        inv[6]  = -m[0]*m[6]*m[15]  + m[0]*m[7]*m[14]  + m[4]*m[2]*m[15] - m[4]*m[3]*m[14] - m[12]*m[2]*m[7]  + m[12]*m[3]*m[6];
        inv[10] =  m[0]*m[5]*m[15]  - m[0]*m[7]*m[13]  - m[4]*m[1]*m[15] + m[4]*m[3]*m[13] + m[12]*m[1]*m[7]  - m[12]*m[3]*m[5];
        inv[14] = -m[0]*m[5]*m[14]  + m[0]*m[6]*m[13]  + m[4]*m[1]*m[14] - m[4]*m[2]*m[13] - m[12]*m[1]*m[6]  + m[12]*m[2]*m[5];
        inv[3]  = -m[1]*m[6]*m[11]  + m[1]*m[7]*m[10]  + m[5]*m[2]*m[11] - m[5]*m[3]*m[10] - m[9]*m[2]*m[7]   + m[9]*m[3]*m[6];
        inv[7]  =  m[0]*m[6]*m[11]  - m[0]*m[7]*m[10]  - m[4]*m[2]*m[11] + m[4]*m[3]*m[10] + m[8]*m[2]*m[7]   - m[8]*m[3]*m[6];
        inv[11] = -m[0]*m[5]*m[11]  + m[0]*m[7]*m[9]   + m[4]*m[1]*m[11] - m[4]*m[3]*m[9]  - m[8]*m[1]*m[7]   + m[8]*m[3]*m[5];
        inv[15] =  m[0]*m[5]*m[10]  - m[0]*m[6]*m[9]   - m[4]*m[1]*m[10] + m[4]*m[2]*m[9]  + m[8]*m[1]*m[6]   - m[8]*m[2]*m[5];

        float det = m[0]*inv[0] + m[1]*inv[4] + m[2]*inv[8] + m[3]*inv[12];
        float rdet = 1.0f / det;

        #pragma unroll
        for (int r = 0; r < 4; r++) {
            #pragma unroll
            for (int c = 0; c < 4; c++) {
                float a = 0.0f;
                #pragma unroll
                for (int k = 0; k < 4; k++) a += inv[4*r+k] * rdet * E[4*k+c];
                W[4*r+c] = a;
            }
        }
    }

    // ---- transform model points into LDS: p/RES and h = 0.5*|p/RES|^2 (2 pts/thread) ----
    #pragma unroll
    for (int i = tid; i < M_PTS; i += 1024) {
        float x = model[3*i + 0];
        float y = model[3*i + 1];
        float z = model[3*i + 2];
        float X  = W[0]*x + W[1]*y + W[2]*z  + W[3];
        float Y  = W[4]*x + W[5]*y + W[6]*z  + W[7];
        float Z  = W[8]*x + W[9]*y + W[10]*z + W[11];
        float Wd = W[12]*x + W[13]*y + W[14]*z + W[15];
        float rw = 2.0f / Wd;                 // (1/w) * (1/RES)
        float px = X * rw, py = Y * rw, pz = Z * rw;
        float h  = 0.5f * (px*px + py*py + pz*pz);
        sp[i] = make_float4(px, py, pz, h);
    }
    __syncthreads();

    // ---- main: 16 waves x (128-pt chunk); lane covers 4 voxels ----
    const int lane = tid & 63;
    const int wave = tid >> 6;
    const int vbase = blockIdx.x * VPB + lane * VPT;

    float nx[VPT], ny[VPT], nz[VPT], mm[VPT];
    #pragma unroll
    for (int k = 0; k < VPT; k++) {
        int g = vbase + k;
        nx[k] = -centers[3*g + 0] * 2.0f;   // -(c/RES)
        ny[k] = -centers[3*g + 1] * 2.0f;
        nz[k] = -centers[3*g + 2] * 2.0f;
        mm[k] = 1e30f;
    }

    const float4* base = sp + wave * CHUNK;
    #pragma unroll 4
    for (int j = 0; j < CHUNK; ++j) {
        float4 p = base[j];                 // wave-uniform addr -> LDS broadcast
        // t = h - c.p  (d2 = |c|^2 + 2t, monotone in t)
        #pragma unroll
        for (int k = 0; k < VPT; k++)
            mm[k] = fminf(mm[k], fmaf(nx[k], p.x, fmaf(ny[k], p.y, fmaf(nz[k], p.z, p.w))));
    }
    #pragma unroll
    for (int k = 0; k < VPT; k++)
        pmin[wave * VPB + lane * VPT + k] = mm[k];
    __syncthreads();

    // ---- epilogue: threads 0..255 (waves 0..3); thread t owns local voxel t ----
    if (tid < VPB) {
        const int g = blockIdx.x * VPB + tid;
        float m = 1e30f;
        #pragma unroll
        for (int c = 0; c < NWAVES; c++)
            m = fminf(m, pmin[c * VPB + tid]);
        float cx = centers[3*g + 0] * 2.0f;
        float cy = centers[3*g + 1] * 2.0f;
        float cz = centers[3*g + 2] * 2.0f;
        float c2 = cx*cx + cy*cy + cz*cz;
        float d2 = fmaf(2.0f, m, c2);
        float dmin = fminf(sqrtf(fmaxf(d2, 0.0f)), 0.25f);   // clamp at RES/2
        float occ  = fmaxf(1.0f - 4.0f * dmin, 0.0f);

        float mk = masks[g];
        float v0 = occ;
        float v1 = (freev[g] + occ_other[g]) * occ;
        float v2 = mk * occ;
        float v3 = mk;

        #pragma unroll
        for (int off = 32; off > 0; off >>= 1) {
            v0 += __shfl_down(v0, off);
            v1 += __shfl_down(v1, off);
            v2 += __shfl_down(v2, off);
            v3 += __shfl_down(v3, off);
        }
        if (lane == 0) {
            sred[wave*4 + 0] = v0;
            sred[wave*4 + 1] = v1;
            sred[wave*4 + 2] = v2;
            sred[wave*4 + 3] = v3;
        }
    }
    __syncthreads();

    // ---- device-level accumulate + last-block finalize (fence/ticket, proven R5/R6) ----
    if (tid < 4) {
        float s = sred[tid] + sred[4 + tid] + sred[8 + tid] + sred[12 + tid];
        atomicAdd(&acc[tid], s);            // lanes 0..3 of wave 0
    }
    __threadfence();                        // release: acc adds visible before ticket
    if (tid == 0) {
        int old = atomicAdd(ticket, 1);
        if (old == NBLK - 1) {              // last block to finish
            __threadfence();                // acquire
            float ps = atomicAdd(&acc[0], 0.0f);
            float fo = atomicAdd(&acc[1], 0.0f);
            float mo = atomicAdd(&acc[2], 0.0f);
            float ms = atomicAdd(&acc[3], 0.0f);
            float t1 = (ps > 0.0f) ? (fo / ps) : 0.0f;
            float t2 = (ms > 0.0f) ? (mo / ms) : 0.0f;
            out[0] = t1 - t2;
        }
    }
}

extern "C" void kernel_launch(void* const* d_in, const int* in_sizes, int n_in,
                              void* d_out, int out_size, void* d_ws, size_t ws_size,
                              hipStream_t stream) {
    const float* quat      = (const float*)d_in[0];
    const float* tran      = (const float*)d_in[1];
    const float* model     = (const float*)d_in[2];
    const float* view      = (const float*)d_in[3];
    const float* centers   = (const float*)d_in[4];
    const float* freev     = (const float*)d_in[5];
    const float* occ_other = (const float*)d_in[6];
    const float* masks     = (const float*)d_in[7];
    float* out = (float*)d_out;
    float* wsf = (float*)d_ws;

    float* acc    = wsf;                    // 4 floats
    int*   ticket = (int*)(wsf + 4);

    hipMemsetAsync(acc, 0, 5 * sizeof(float), stream);   // zero acc + ticket (capture-legal)
    k_fused<<<NBLK, 1024, 0, stream>>>(quat, tran, model, view, centers, freev,
                                       occ_other, masks, acc, ticket, out);
}

// Round 8
// 83.285 us; speedup vs baseline: 1.7908x; 1.7494x over previous
//
#include <hip/hip_runtime.h>
#include <math.h>

#define M_PTS   2048
#define N_VOX   65536
#define VPT     4                    // voxels per lane
#define VPB     256                  // voxels per block (64 lanes * VPT)
#define NBLK    (N_VOX / VPB)        // 256 blocks (1 per CU)
#define NWAVES  16                   // 1024-thread blocks
#define CHUNK   (M_PTS / NWAVES)     // 128 points per wave

// ws layout (floats): [0, 1024) per-block partials {pred_sum, fo_sum, mask_occ_sum, mask_sum} x 256
// NOTE (R7 post-mortem): do NOT use an in-kernel ticket+__threadfence finalize —
// the device-scope fence tail cost ~65 us across R5/R6/R7. Plain per-block
// partial stores + a second tiny kernel is 5x faster end-to-end.

__global__ __launch_bounds__(1024) void k_fused(const float* __restrict__ quat,
                                                const float* __restrict__ tran,
                                                const float* __restrict__ model,
                                                const float* __restrict__ view,
                                                const float* __restrict__ centers,
                                                const float* __restrict__ freev,
                                                const float* __restrict__ occ_other,
                                                const float* __restrict__ masks,
                                                float* __restrict__ partial) {
    __shared__ float4 sp[M_PTS];             // (x,y,z)/RES, h = 0.5*|p/RES|^2  -> 32 KB
    __shared__ float  pmin[NWAVES * VPB];    // [chunk][local voxel]            -> 16 KB
    __shared__ float  sred[16];              // cross-wave sum combine

    const int tid = threadIdx.x;

    // ---- per-block uniform prep: W = inv(view) * quat_matrix (redundant on all threads) ----
    float W[16];
    {
        float q0 = quat[0], q1 = quat[1], q2 = quat[2], q3 = quat[3];
        float nq = q0*q0 + q1*q1 + q2*q2 + q3*q3;
        float s = sqrtf(2.0f / nq);
        q0 *= s; q1 *= s; q2 *= s; q3 *= s;
        float E[16];
        E[0]  = 1.0f - q2*q2 - q3*q3; E[1]  = q1*q2 - q3*q0;        E[2]  = q1*q3 + q2*q0;        E[3]  = tran[0];
        E[4]  = q1*q2 + q3*q0;        E[5]  = 1.0f - q1*q1 - q3*q3; E[6]  = q2*q3 - q1*q0;        E[7]  = tran[1];
        E[8]  = q1*q3 - q2*q0;        E[9]  = q2*q3 + q1*q0;        E[10] = 1.0f - q1*q1 - q2*q2; E[11] = tran[2];
        E[12] = 0.0f; E[13] = 0.0f; E[14] = 0.0f; E[15] = 1.0f;

        float m[16], inv[16];
        #pragma unroll
        for (int i = 0; i < 16; i++) m[i] = view[i];

        inv[0]  =  m[5]*m[10]*m[15] - m[5]*m[11]*m[14] - m[9]*m[6]*m[15] + m[9]*m[7]*m[14] + m[13]*m[6]*m[11] - m[13]*m[7]*m[10];
        inv[4]  = -m[4]*m[10]*m[15] + m[4]*m[11]*m[14] + m[8]*m[6]*m[15] - m[8]*m[7]*m[14] - m[12]*m[6]*m[11] + m[12]*m[7]*m[10];
        inv[8]  =  m[4]*m[9]*m[15]  - m[4]*m[11]*m[13] - m[8]*m[5]*m[15] + m[8]*m[7]*m[13] + m[12]*m[5]*m[11] - m[12]*m[7]*m[9];
        inv[12] = -m[4]*m[9]*m[14]  + m[4]*m[10]*m[13] + m[8]*m[5]*m[14] - m[8]*m[6]*m[13] - m[12]*m[5]*m[10] + m[12]*m[6]*m[9];
        inv[1]  = -m[1]*m[10]*m[15] + m[1]*m[11]*m[14] + m[9]*m[2]*m[15] - m[9]*m[3]*m[14] - m[13]*m[2]*m[11] + m[13]*m[3]*m[10];
        inv[5]  =  m[0]*m[10]*m[15] - m[0]*m[11]*m[14] - m[8]*m[2]*m[15] + m[8]*m[3]*m[14] + m[12]*m[2]*m[11] - m[12]*m[3]*m[10];
        inv[9]  = -m[0]*m[9]*m[15]  + m[0]*m[11]*m[13] + m[8]*m[1]*m[15] - m[8]*m[3]*m[13] - m[12]*m[1]*m[11] + m[12]*m[3]*m[9];
        inv[13] =  m[0]*m[9]*m[14]  - m[0]*m[10]*m[13] - m[8]*m[1]*m[14] + m[8]*m[2]*m[13] + m[12]*m[1]*m[10] - m[12]*m[2]*m[9];
        inv[2]  =  m[1]*m[6]*m[15]  - m[1]*m[7]*m[14]  - m[5]*m[2]*m[15] + m[5]*m[3]*m[14] + m[13]*m[2]*m[7]  - m[13]*m[3]*m[6];
        inv[6]  = -m[0]*m[6]*m[15]  + m[0]*m[7]*m[14]  + m[4]*m[2]*m[15] - m[4]*m[3]*m[14] - m[12]*m[2]*m[7]  + m[12]*m[3]*m[6];
        inv[10] =  m[0]*m[5]*m[15]  - m[0]*m[7]*m[13]  - m[4]*m[1]*m[15] + m[4]*m[3]*m[13] + m[12]*m[1]*m[7]  - m[12]*m[3]*m[5];
        inv[14] = -m[0]*m[5]*m[14]  + m[0]*m[6]*m[13]  + m[4]*m[1]*m[14] - m[4]*m[2]*m[13] - m[12]*m[1]*m[6]  + m[12]*m[2]*m[5];
        inv[3]  = -m[1]*m[6]*m[11]  + m[1]*m[7]*m[10]  + m[5]*m[2]*m[11] - m[5]*m[3]*m[10] - m[9]*m[2]*m[7]   + m[9]*m[3]*m[6];
        inv[7]  =  m[0]*m[6]*m[11]  - m[0]*m[7]*m[10]  - m[4]*m[2]*m[11] + m[4]*m[3]*m[10] + m[8]*m[2]*m[7]   - m[8]*m[3]*m[6];
        inv[11] = -m[0]*m[5]*m[11]  + m[0]*m[7]*m[9]   + m[4]*m[1]*m[11] - m[4]*m[3]*m[9]  - m[8]*m[1]*m[7]   + m[8]*m[3]*m[5];
        inv[15] =  m[0]*m[5]*m[10]  - m[0]*m[6]*m[9]   - m[4]*m[1]*m[10] + m[4]*m[2]*m[9]  + m[8]*m[1]*m[6]   - m[8]*m[2]*m[5];

        float det = m[0]*inv[0] + m[1]*inv[4] + m[2]*inv[8] + m[3]*inv[12];
        float rdet = 1.0f / det;

        #pragma unroll
        for (int r = 0; r < 4; r++) {
            #pragma unroll
            for (int c = 0; c < 4; c++) {
                float a = 0.0f;
                #pragma unroll
                for (int k = 0; k < 4; k++) a += inv[4*r+k] * rdet * E[4*k+c];
                W[4*r+c] = a;
            }
        }
    }

    // ---- transform model points into LDS: p/RES and h = 0.5*|p/RES|^2 (2 pts/thread) ----
    #pragma unroll
    for (int i = tid; i < M_PTS; i += 1024) {
        float x = model[3*i + 0];
        float y = model[3*i + 1];
        float z = model[3*i + 2];
        float X  = W[0]*x + W[1]*y + W[2]*z  + W[3];
        float Y  = W[4]*x + W[5]*y + W[6]*z  + W[7];
        float Z  = W[8]*x + W[9]*y + W[10]*z + W[11];
        float Wd = W[12]*x + W[13]*y + W[14]*z + W[15];
        float rw = 2.0f / Wd;                 // (1/w) * (1/RES)
        float px = X * rw, py = Y * rw, pz = Z * rw;
        float h  = 0.5f * (px*px + py*py + pz*pz);
        sp[i] = make_float4(px, py, pz, h);
    }
    __syncthreads();

    // ---- main: 16 waves x (128-pt chunk); lane covers 4 voxels ----
    const int lane = tid & 63;
    const int wave = tid >> 6;
    const int vbase = blockIdx.x * VPB + lane * VPT;

    float nx[VPT], ny[VPT], nz[VPT], mm[VPT];
    #pragma unroll
    for (int k = 0; k < VPT; k++) {
        int g = vbase + k;
        nx[k] = -centers[3*g + 0] * 2.0f;   // -(c/RES)
        ny[k] = -centers[3*g + 1] * 2.0f;
        nz[k] = -centers[3*g + 2] * 2.0f;
        mm[k] = 1e30f;
    }

    const float4* base = sp + wave * CHUNK;
    #pragma unroll 4
    for (int j = 0; j < CHUNK; ++j) {
        float4 p = base[j];                 // wave-uniform addr -> LDS broadcast
        // t = h - c.p  (d2 = |c|^2 + 2t, monotone in t)
        #pragma unroll
        for (int k = 0; k < VPT; k++)
            mm[k] = fminf(mm[k], fmaf(nx[k], p.x, fmaf(ny[k], p.y, fmaf(nz[k], p.z, p.w))));
    }
    #pragma unroll
    for (int k = 0; k < VPT; k++)
        pmin[wave * VPB + lane * VPT + k] = mm[k];
    __syncthreads();

    // ---- epilogue: threads 0..255, thread t owns local voxel t ----
    if (tid < VPB) {
        const int g = blockIdx.x * VPB + tid;
        float m = 1e30f;
        #pragma unroll
        for (int c = 0; c < NWAVES; c++)
            m = fminf(m, pmin[c * VPB + tid]);
        float cx = centers[3*g + 0] * 2.0f;
        float cy = centers[3*g + 1] * 2.0f;
        float cz = centers[3*g + 2] * 2.0f;
        float c2 = cx*cx + cy*cy + cz*cz;
        float d2 = fmaf(2.0f, m, c2);
        float dmin = fminf(sqrtf(fmaxf(d2, 0.0f)), 0.25f);   // clamp at RES/2
        float occ  = fmaxf(1.0f - 4.0f * dmin, 0.0f);

        float mk = masks[g];
        float v0 = occ;
        float v1 = (freev[g] + occ_other[g]) * occ;
        float v2 = mk * occ;
        float v3 = mk;

        #pragma unroll
        for (int off = 32; off > 0; off >>= 1) {
            v0 += __shfl_down(v0, off);
            v1 += __shfl_down(v1, off);
            v2 += __shfl_down(v2, off);
            v3 += __shfl_down(v3, off);
        }
        if (lane == 0) {
            sred[wave*4 + 0] = v0;
            sred[wave*4 + 1] = v1;
            sred[wave*4 + 2] = v2;
            sred[wave*4 + 3] = v3;
        }
    }
    __syncthreads();
    if (tid < 4) {
        float s = sred[tid] + sred[4 + tid] + sred[8 + tid] + sred[12 + tid];
        partial[blockIdx.x * 4 + tid] = s;
    }
}

__global__ __launch_bounds__(256) void k_final(const float* __restrict__ partial,
                                               float* __restrict__ out) {
    __shared__ float sred[16];
    const int tid  = threadIdx.x;
    const int lane = tid & 63;
    const int wave = tid >> 6;

    float4 p = ((const float4*)partial)[tid];   // one block's 4 partials per thread
    float v0 = p.x, v1 = p.y, v2 = p.z, v3 = p.w;

    #pragma unroll
    for (int off = 32; off > 0; off >>= 1) {
        v0 += __shfl_down(v0, off);
        v1 += __shfl_down(v1, off);
        v2 += __shfl_down(v2, off);
        v3 += __shfl_down(v3, off);
    }
    if (lane == 0) {
        sred[wave*4 + 0] = v0;
        sred[wave*4 + 1] = v1;
        sred[wave*4 + 2] = v2;
        sred[wave*4 + 3] = v3;
    }
    __syncthreads();
    if (tid == 0) {
        float ps = sred[0] + sred[4] + sred[8]  + sred[12];
        float fo = sred[1] + sred[5] + sred[9]  + sred[13];
        float mo = sred[2] + sred[6] + sred[10] + sred[14];
        float ms = sred[3] + sred[7] + sred[11] + sred[15];
        float t1 = (ps > 0.0f) ? (fo / ps) : 0.0f;
        float t2 = (ms > 0.0f) ? (mo / ms) : 0.0f;
        out[0] = t1 - t2;
    }
}

extern "C" void kernel_launch(void* const* d_in, const int* in_sizes, int n_in,
                              void* d_out, int out_size, void* d_ws, size_t ws_size,
                              hipStream_t stream) {
    const float* quat      = (const float*)d_in[0];
    const float* tran      = (const float*)d_in[1];
    const float* model     = (const float*)d_in[2];
    const float* view      = (const float*)d_in[3];
    const float* centers   = (const float*)d_in[4];
    const float* freev     = (const float*)d_in[5];
    const float* occ_other = (const float*)d_in[6];
    const float* masks     = (const float*)d_in[7];
    float* out     = (float*)d_out;
    float* partial = (float*)d_ws;   // 1024 floats, fully overwritten by k_fused

    k_fused<<<NBLK, 1024, 0, stream>>>(quat, tran, model, view, centers, freev,
                                       occ_other, masks, partial);
    k_final<<<1, 256, 0, stream>>>(partial, out);
}